// Round 2
// baseline (492.790 us; speedup 1.0000x reference)
//
#include <hip/hip_runtime.h>

#define RES 256
#define NV 6890
#define CAP 32                         // max verts tracked per 8^3 cell (E[n]≈0.4, P(>32)≈1e-35)
#define NCELL (32*32*32)
#define SEM_ELEMS (RES*RES*RES*3)
#define WSUM_ELEMS (RES*RES*RES)

// ---------------------------------------------------------------------------
// Kernel 1: zero the per-cell vertex counters (d_ws is poisoned every call).
// ---------------------------------------------------------------------------
__global__ void svox_zero_counts(int* __restrict__ counts) {
    int i = blockIdx.x * blockDim.x + threadIdx.x;
    if (i < NCELL) counts[i] = 0;
}

// ---------------------------------------------------------------------------
// Kernel 2: bucket vertices by the 8^3-voxel cell containing their integer
// center = floor((v+0.5)*256). Centers outside the grid clamp to boundary
// cells; the gather-side |voxel-center|<=3 check rejects any false matches.
// ---------------------------------------------------------------------------
__global__ void svox_bucket(const float* __restrict__ verts,
                            int* __restrict__ counts,
                            int* __restrict__ lists) {
    int n = blockIdx.x * blockDim.x + threadIdx.x;
    if (n >= NV) return;
    float px = (verts[3 * n + 0] + 0.5f) * 256.0f;
    float py = (verts[3 * n + 1] + 0.5f) * 256.0f;
    float pz = (verts[3 * n + 2] + 0.5f) * 256.0f;
    int cx = (int)floorf(px), cy = (int)floorf(py), cz = (int)floorf(pz);
    int bx = min(max(cx >> 3, 0), 31);
    int by = min(max(cy >> 3, 0), 31);
    int bz = min(max(cz >> 3, 0), 31);
    int cell = (bx << 10) | (by << 5) | bz;
    int slot = atomicAdd(&counts[cell], 1);
    if (slot < CAP) lists[cell * CAP + slot] = n;
}

// ---------------------------------------------------------------------------
// Kernel 3: gather. One thread per voxel. Writes every output element exactly
// once (doubles as the initializer). No atomics.
// ---------------------------------------------------------------------------
__global__ void __launch_bounds__(256)
svox_gather(const float* __restrict__ verts,
            const float* __restrict__ codes,
            const float* __restrict__ occ,
            const int* __restrict__ counts,
            const int* __restrict__ lists,
            float* __restrict__ sem,
            float* __restrict__ wsum) {
    int lin = blockIdx.x * blockDim.x + threadIdx.x;     // 16,777,216 threads
    int z = lin & 255;
    int y = (lin >> 8) & 255;
    int x = lin >> 16;

    float occv = __builtin_nontemporal_load(&occ[lin]);

    float a0 = 0.0f, a1 = 0.0f, a2 = 0.0f, aw = 0.0f;

    if (occv > 0.0f) {
        const float inv = 1.0f / 256.0f;
        float fx = ((float)x + 0.5f) * inv - 0.5f;       // voxel center coords
        float fy = ((float)y + 0.5f) * inv - 0.5f;
        float fz = ((float)z + 0.5f) * inv - 0.5f;

        // cells that can hold a vertex center in [x-3, x+3] (<=2 per axis)
        int xc0 = max(x - 3, 0) >> 3, xc1 = min(x + 3, 255) >> 3;
        int yc0 = max(y - 3, 0) >> 3, yc1 = min(y + 3, 255) >> 3;
        int zc0 = max(z - 3, 0) >> 3, zc1 = min(z + 3, 255) >> 3;

        for (int bx = xc0; bx <= xc1; ++bx)
        for (int by = yc0; by <= yc1; ++by)
        for (int bz = zc0; bz <= zc1; ++bz) {
            int cell = (bx << 10) | (by << 5) | bz;
            int cnt = counts[cell];
            cnt = min(cnt, CAP);
            int base = cell * CAP;
            for (int j = 0; j < cnt; ++j) {
                int n = lists[base + j];
                float vx = verts[3 * n + 0];
                float vy = verts[3 * n + 1];
                float vz = verts[3 * n + 2];
                int cxx = (int)floorf((vx + 0.5f) * 256.0f);
                int cyy = (int)floorf((vy + 0.5f) * 256.0f);
                int czz = (int)floorf((vz + 0.5f) * 256.0f);
                unsigned dxi = (unsigned)(x - cxx + 3);
                unsigned dyi = (unsigned)(y - cyy + 3);
                unsigned dzi = (unsigned)(z - czz + 3);
                if (dxi > 6u || dyi > 6u || dzi > 6u) continue;
                float dx = fx - vx, dy = fy - vy, dz = fz - vz;
                float d2 = dx * dx + dy * dy + dz * dz;
                float w = __expf(-8192.0f * d2);         // 2*sigma^2 = 1/8192
                a0 += w * codes[3 * n + 0];
                a1 += w * codes[3 * n + 1];
                a2 += w * codes[3 * n + 2];
                aw += w;
            }
        }
    }

    __builtin_nontemporal_store(a0, &sem[3 * lin + 0]);
    __builtin_nontemporal_store(a1, &sem[3 * lin + 1]);
    __builtin_nontemporal_store(a2, &sem[3 * lin + 2]);
    __builtin_nontemporal_store(0.001f + aw, &wsum[lin]);
}

extern "C" void kernel_launch(void* const* d_in, const int* in_sizes, int n_in,
                              void* d_out, int out_size, void* d_ws, size_t ws_size,
                              hipStream_t stream) {
    const float* verts = (const float*)d_in[0];   // (6890,3) f32
    const float* codes = (const float*)d_in[1];   // (6890,3) f32
    const float* occ   = (const float*)d_in[2];   // (256,256,256) f32
    // d_in[3] = smpl_faces (unused by the reference computation)

    float* sem  = (float*)d_out;                  // (256,256,256,3)
    float* wsum = (float*)d_out + SEM_ELEMS;      // (256,256,256)

    int* counts = (int*)d_ws;                     // 32768 ints
    int* lists  = counts + NCELL;                 // 32768 * CAP ints (~4.2 MB)

    svox_zero_counts<<<(NCELL + 255) / 256, 256, 0, stream>>>(counts);
    svox_bucket<<<(NV + 255) / 256, 256, 0, stream>>>(verts, counts, lists);
    svox_gather<<<(RES * RES * RES) / 256, 256, 0, stream>>>(
        verts, codes, occ, counts, lists, sem, wsum);
}

// Round 5
// 390.714 us; speedup vs baseline: 1.2613x; 1.2613x over previous
//
#include <hip/hip_runtime.h>

#define RES 256
#define NV 6890
#define CAP 16                         // max verts per 8^3 cell (mean 0.41, Poisson tail ~1e-15)
#define NCELL (32*32*32)
#define SEM_ELEMS (RES*RES*RES*3)

typedef float f32x4 __attribute__((ext_vector_type(4)));

// ---------------------------------------------------------------------------
// Kernel 1: zero the per-cell counters (d_ws is re-poisoned before every call).
// ---------------------------------------------------------------------------
__global__ void svox_zero_counts(int* __restrict__ counts) {
    int i = blockIdx.x * blockDim.x + threadIdx.x;
    if (i < NCELL) counts[i] = 0;
}

// ---------------------------------------------------------------------------
// Kernel 2: bucket vertices into 8^3-voxel cells, storing a packed record:
//   rec0 = (vx, vy, vz, bitcast((cx+8)<<20 | (cy+8)<<10 | (cz+8)))
//   rec1 = (c0, c1, c2, 0)
// Center bias +8, clamped to [0,1023]: clamped values can never pass the
// |voxel - center| <= 3 window test, so edge clamping is value-exact.
// ---------------------------------------------------------------------------
__global__ void svox_bucket(const float* __restrict__ verts,
                            const float* __restrict__ codes,
                            int* __restrict__ counts,
                            f32x4* __restrict__ lists) {
    int n = blockIdx.x * blockDim.x + threadIdx.x;
    if (n >= NV) return;
    float vx = verts[3 * n + 0], vy = verts[3 * n + 1], vz = verts[3 * n + 2];
    int cx = (int)floorf((vx + 0.5f) * 256.0f);
    int cy = (int)floorf((vy + 0.5f) * 256.0f);
    int cz = (int)floorf((vz + 0.5f) * 256.0f);
    int px = min(max(cx + 8, 0), 1023);
    int py = min(max(cy + 8, 0), 1023);
    int pz = min(max(cz + 8, 0), 1023);
    int bx = min(max(cx >> 3, 0), 31);
    int by = min(max(cy >> 3, 0), 31);
    int bz = min(max(cz >> 3, 0), 31);
    int cell = (bx << 10) | (by << 5) | bz;
    int slot = atomicAdd(&counts[cell], 1);
    if (slot < CAP) {
        int pk = (px << 20) | (py << 10) | pz;
        f32x4 r0 = {vx, vy, vz, __int_as_float(pk)};
        f32x4 r1 = {codes[3 * n + 0], codes[3 * n + 1], codes[3 * n + 2], 0.0f};
        lists[(cell * CAP + slot) * 2 + 0] = r0;
        lists[(cell * CAP + slot) * 2 + 1] = r1;
    }
}

// ---------------------------------------------------------------------------
// Kernel 3: gather, one thread per 4 consecutive z-voxels. Writes every
// output element exactly once (doubles as initializer). No atomics.
// ---------------------------------------------------------------------------
__global__ void __launch_bounds__(256)
svox_gather(const float* __restrict__ occ,
            const int* __restrict__ counts,
            const f32x4* __restrict__ lists,
            f32x4* __restrict__ sem4,
            f32x4* __restrict__ wsum4) {
    int t = blockIdx.x * blockDim.x + threadIdx.x;   // 4,194,304 threads
    int lin0 = t << 2;
    int z0 = lin0 & 255;                             // multiple of 4
    int y  = (lin0 >> 8) & 255;
    int x  = lin0 >> 16;

    // acc[q][0..2] = sem channels, acc[q][3] = weight (all indices unrolled-static)
    float acc[4][4];
#pragma unroll
    for (int q = 0; q < 4; ++q) {
        acc[q][0] = 0.f; acc[q][1] = 0.f; acc[q][2] = 0.f; acc[q][3] = 0.f;
    }

    // cells that can hold a center within the windows of voxels z0..z0+3
    int xc0 = max(x - 3, 0) >> 3,  xc1 = min(x + 3, 255) >> 3;
    int yc0 = max(y - 3, 0) >> 3,  yc1 = min(y + 3, 255) >> 3;
    int zc0 = max(z0 - 3, 0) >> 3, zc1 = min(z0 + 6, 255) >> 3;

    int total = 0;
    for (int bx = xc0; bx <= xc1; ++bx)
        for (int by = yc0; by <= yc1; ++by)
            for (int bz = zc0; bz <= zc1; ++bz)
                total += counts[(bx << 10) | (by << 5) | bz];

    if (total > 0) {
        const float inv = 1.0f / 256.0f;
        float fx  = ((float)x  + 0.5f) * inv - 0.5f;
        float fy  = ((float)y  + 0.5f) * inv - 0.5f;
        float fz0 = ((float)z0 + 0.5f) * inv - 0.5f;

        const f32x4 o4 = __builtin_nontemporal_load((const f32x4*)&occ[lin0]);
        float occv[4] = {o4.x, o4.y, o4.z, o4.w};

        for (int bx = xc0; bx <= xc1; ++bx)
        for (int by = yc0; by <= yc1; ++by)
        for (int bz = zc0; bz <= zc1; ++bz) {
            int cell = (bx << 10) | (by << 5) | bz;
            int cnt = min(counts[cell], CAP);
            int base = cell * CAP;
            for (int j = 0; j < cnt; ++j) {
                f32x4 r0 = lists[(base + j) * 2 + 0];
                f32x4 r1 = lists[(base + j) * 2 + 1];
                int pk = __float_as_int(r0.w);
                int cxb = (pk >> 20) & 1023;          // cx + 8
                int cyb = (pk >> 10) & 1023;          // cy + 8
                int czb =  pk        & 1023;          // cz + 8
                unsigned dxi = (unsigned)(x  + 8 - cxb + 3);
                unsigned dyi = (unsigned)(y  + 8 - cyb + 3);
                unsigned dzq = (unsigned)(z0 + 8 - czb + 6);  // in [0,9] if any q matches
                if (dxi > 6u || dyi > 6u || dzq > 9u) continue;

                float dx = fx - r0.x, dy = fy - r0.y;
                float exy = __expf(-8192.0f * (dx * dx + dy * dy));
                int czr = czb - 8;                    // real center z
#pragma unroll
                for (int q = 0; q < 4; ++q) {
                    unsigned dzi = (unsigned)(z0 + q - czr + 3);
                    if (dzi > 6u) continue;
                    if (occv[q] <= 0.0f) continue;
                    float dz = fz0 + (float)q * inv - r0.z;
                    float w = exy * __expf(-8192.0f * dz * dz);
                    acc[q][0] += w * r1.x;
                    acc[q][1] += w * r1.y;
                    acc[q][2] += w * r1.z;
                    acc[q][3] += w;
                }
            }
        }
    }

    f32x4 s0 = {acc[0][0], acc[0][1], acc[0][2], acc[1][0]};
    f32x4 s1 = {acc[1][1], acc[1][2], acc[2][0], acc[2][1]};
    f32x4 s2 = {acc[2][2], acc[3][0], acc[3][1], acc[3][2]};
    f32x4 sw = {0.001f + acc[0][3], 0.001f + acc[1][3],
                0.001f + acc[2][3], 0.001f + acc[3][3]};
    __builtin_nontemporal_store(s0, &sem4[t * 3 + 0]);
    __builtin_nontemporal_store(s1, &sem4[t * 3 + 1]);
    __builtin_nontemporal_store(s2, &sem4[t * 3 + 2]);
    __builtin_nontemporal_store(sw, &wsum4[t]);
}

extern "C" void kernel_launch(void* const* d_in, const int* in_sizes, int n_in,
                              void* d_out, int out_size, void* d_ws, size_t ws_size,
                              hipStream_t stream) {
    const float* verts = (const float*)d_in[0];   // (6890,3) f32
    const float* codes = (const float*)d_in[1];   // (6890,3) f32
    const float* occ   = (const float*)d_in[2];   // (256,256,256) f32
    // d_in[3] = smpl_faces (unused by the reference computation)

    f32x4* sem4  = (f32x4*)d_out;                       // 12,582,912 f32x4
    f32x4* wsum4 = (f32x4*)((float*)d_out + SEM_ELEMS); // 4,194,304 f32x4

    int*   counts = (int*)d_ws;                   // 32768 ints
    f32x4* lists  = (f32x4*)(counts + NCELL);     // 32768 * CAP * 2 f32x4 = 16 MB

    svox_zero_counts<<<(NCELL + 255) / 256, 256, 0, stream>>>(counts);
    svox_bucket<<<(NV + 255) / 256, 256, 0, stream>>>(verts, codes, counts, lists);
    svox_gather<<<(RES * RES * RES / 4) / 256, 256, 0, stream>>>(
        occ, counts, lists, sem4, wsum4);
}